// Round 9
// baseline (245.765 us; speedup 1.0000x reference)
//
#include <hip/hip_runtime.h>
#include <hip/hip_bf16.h>

#define NS 64
#define NP 32
#define DIM 128
#define BATCH_N 16384

typedef float f32x4 __attribute__((ext_vector_type(4)));
typedef _Float16 f16x8 __attribute__((ext_vector_type(8)));
typedef unsigned int u32;
typedef unsigned long long u64;

// fp32 -> fp16 (RNE via hardware cvt)
__device__ __forceinline__ unsigned short f2h(float f) {
    _Float16 h = (_Float16)f;
    return __builtin_bit_cast(unsigned short, h);
}

// ---------------------------------------------------------------------------
// prep 1: pair-compressed fp16 MFMA A-operand fragments (layout as R6).
//   t0 = A0@B0            t1 = (A1-A0)@B0      (factor b0)
//   t2 = A0@(B1-B0)       t3 = (A1-A0)@(B1-B0) (factor b0*b1)
// element idx = ((((p*8 + mm)*2 + H)*4 + t)*2 + kq)*512 + lane*8 + j
// kk = 2H+kq, k = kk*32 + (lane>>4)*8 + j, m = mm*16 + (lane&15).
// ---------------------------------------------------------------------------
__global__ __launch_bounds__(256)
void prep_pair_frags(const float* __restrict__ data,
                     unsigned short* __restrict__ afrag) {
    __shared__ float LA[2 * 32 * 129];
    __shared__ float LB[2 * 32 * 68];

    const int p   = blockIdx.x >> 3;
    const int kk  = (blockIdx.x >> 1) & 3;
    const int mh  = blockIdx.x & 1;
    const int tid = threadIdx.x;
    const int kgrp = tid >> 4;
    const int mgrp = tid & 15;

    const float* A0 = data + ((size_t)(2 * p) * 2 + 0) * DIM * DIM;
    const float* A1 = A0 + DIM * DIM;
    const float* B0 = data + ((size_t)(2 * p + 1) * 2 + 0) * DIM * DIM;
    const float* B1 = B0 + DIM * DIM;

    for (int c = tid; c < 32 * DIM; c += 256) {
        int kl = c >> 7, j = c & 127;
        float a0 = A0[(kk * 32 + kl) * DIM + j];
        float a1 = A1[(kk * 32 + kl) * DIM + j];
        LA[kl * 129 + j] = a0;
        LA[32 * 129 + kl * 129 + j] = a1 - a0;
    }

    float acc[2][2][2][4];
#pragma unroll
    for (int L = 0; L < 2; ++L)
#pragma unroll
        for (int R = 0; R < 2; ++R)
#pragma unroll
            for (int i = 0; i < 2; ++i)
#pragma unroll
                for (int mi = 0; mi < 4; ++mi) acc[L][R][i][mi] = 0.f;

    for (int ch = 0; ch < 4; ++ch) {
        __syncthreads();
        for (int c = tid; c < 32 * 64; c += 256) {
            int jl = c >> 6, ml = c & 63;
            float b0 = B0[(ch * 32 + jl) * DIM + mh * 64 + ml];
            float b1 = B1[(ch * 32 + jl) * DIM + mh * 64 + ml];
            LB[jl * 68 + ml] = b0;
            LB[32 * 68 + jl * 68 + ml] = b1 - b0;
        }
        __syncthreads();
#pragma unroll 2
        for (int jl = 0; jl < 32; ++jl) {
            int j = ch * 32 + jl;
            float la0[2], la1[2];
#pragma unroll
            for (int i = 0; i < 2; ++i) {
                la0[i] = LA[(kgrp * 2 + i) * 129 + j];
                la1[i] = LA[32 * 129 + (kgrp * 2 + i) * 129 + j];
            }
            f32x4 lb0 = *reinterpret_cast<const f32x4*>(&LB[jl * 68 + mgrp * 4]);
            f32x4 lb1 = *reinterpret_cast<const f32x4*>(&LB[32 * 68 + jl * 68 + mgrp * 4]);
#pragma unroll
            for (int i = 0; i < 2; ++i)
#pragma unroll
                for (int mi = 0; mi < 4; ++mi) {
                    acc[0][0][i][mi] += la0[i] * lb0[mi];
                    acc[1][0][i][mi] += la1[i] * lb0[mi];
                    acc[0][1][i][mi] += la0[i] * lb1[mi];
                    acc[1][1][i][mi] += la1[i] * lb1[mi];
                }
        }
    }

    const int H  = kk >> 1;
    const int kq = kk & 1;
#pragma unroll
    for (int t = 0; t < 4; ++t) {
        int L = t & 1, R = t >> 1;
#pragma unroll
        for (int i = 0; i < 2; ++i)
#pragma unroll
            for (int mi = 0; mi < 4; ++mi) {
                int k = kk * 32 + kgrp * 2 + i;
                int m = mh * 64 + mgrp * 4 + mi;
                int mm = m >> 4;
                int lane = ((k & 31) >> 3) * 16 + (m & 15);
                int jj = k & 7;
                size_t idx =
                    ((size_t)((((p * 8 + mm) * 2 + H) * 4 + t) * 2 + kq)) * 512 +
                    lane * 8 + jj;
                afrag[idx] = f2h(acc[L][R][i][mi]);
            }
    }
}

// ---------------------------------------------------------------------------
// prep 2: pack occupation bits, one u64 per batch row
// ---------------------------------------------------------------------------
__global__ void prep_bits(const int* __restrict__ onstate,
                          const int* __restrict__ image2,
                          u64* __restrict__ bits) {
    int r = blockIdx.x * blockDim.x + threadIdx.x;
    if (r >= BATCH_N) return;
    const int* row = onstate + (size_t)r * NS;
    u64 b = 0;
#pragma unroll 8
    for (int t = 0; t < NS; ++t) {
        b |= ((u64)(row[image2[t]] & 1)) << t;
    }
    bits[r] = b;
}

// ---------------------------------------------------------------------------
// main: 256 blocks x 1024 threads (16 waves, 4/SIMD), 64 rows/block,
// 1 block/CU. Wave (mt = wid>>1, kh = wid&1): m-tile 16 x K-half 64.
// A-frags: 8 dwordx4/wave/pair, no duplication (128 KB/CU-pair on VMEM).
// Cross-kh partial sums exchanged via 16 KB LDS buffer, 2 rounds:
//   round R: kh0 writes rg R, kh1 writes rg 2+R; barrier; partner adds,
//   completes its kept rows-half, packs fp16 v_new; barrier.
// ---------------------------------------------------------------------------
__global__ __launch_bounds__(1024, 4)
void mps_pair(const unsigned short* __restrict__ afrag,
              const u64* __restrict__ occbits,
              const float* __restrict__ left,
              const float* __restrict__ right,
              float* __restrict__ out) {
    __shared__ char smem[49152];   // [0,32K): v dbuf (fp16, swizzled); [32K,48K): exchange

    const int tid  = threadIdx.x;
    const int wid  = tid >> 6;          // 0..15
    const int mt   = wid >> 1;          // 0..7: m-tile
    const int kh   = wid & 1;           // 0..1: K-half
    const int lane = tid & 63;
    const int li   = lane & 15;
    const int g    = lane >> 4;
    const int rbase = blockIdx.x * 64;

    u64 bits[4];
#pragma unroll
    for (int rg = 0; rg < 4; ++rg)
        bits[rg] = occbits[rbase + rg * 16 + li];

    // A-frag element voffset (saddr layout), +2048 centers imm range
    const int voff = mt * 8192 + kh * 4096 + 2048 + lane * 8;

    // v-read byte offsets [kq][rg]
    u32 rdoff[2][4];
#pragma unroll
    for (int kq = 0; kq < 2; ++kq)
#pragma unroll
        for (int rg = 0; rg < 4; ++rg) {
            int r = rg * 16 + li;
            int kk = kh * 2 + kq;
            rdoff[kq][rg] =
                (u32)(r * 256 + kk * 64 + g * 16) ^ ((u32)(r & 7) << 4);
        }

    // exchange offsets (same (li,g) mapping both sides; g XOR li&3 de-banks)
    const u32 exoff_w = (u32)((mt * 2 + kh) * 1024 + li * 64 + ((g ^ (li & 3)) << 4));
    const u32 exoff_r = (u32)((mt * 2 + (kh ^ 1)) * 1024 + li * 64 + ((g ^ (li & 3)) << 4));

    // v-write offsets for kept rg per round: kept = (kh?0:2)+R
    u32 wroff[2];
#pragma unroll
    for (int R = 0; R < 2; ++R) {
        int rgk = (kh ? 0 : 2) + R;
        int r = rgk * 16 + li;
        wroff[R] = (u32)(r * 256 + (mt * 16 + g * 4) * 2) ^ ((u32)(r & 7) << 4);
    }

    // init v buffer 0 with fp16(left), swizzled; 1024 threads = 64 rows x 16 chunks
    {
        int r  = tid >> 4;
        int kc = tid & 15;
        unsigned short tmp[8];
#pragma unroll
        for (int j = 0; j < 8; ++j) tmp[j] = f2h(left[kc * 8 + j]);
        u32 byte = (u32)(r * 256 + kc * 16) ^ ((u32)(r & 7) << 4);
        *reinterpret_cast<uint4*>(smem + byte) = *reinterpret_cast<uint4*>(tmp);
    }
    __syncthreads();

    const f16x8 zf = {0, 0, 0, 0, 0, 0, 0, 0};
    f16x8 A[4][2];     // [t][kq] single buffer; reloaded during exchange phase
    float pvs[2] = {0.f, 0.f};

#define ISSUE(P_)                                                             \
    {                                                                         \
        const unsigned short* pb = afrag + (size_t)(P_)*65536 + voff;         \
        _Pragma("unroll")                                                     \
        for (int t = 0; t < 4; ++t)                                           \
            _Pragma("unroll")                                                 \
            for (int kq = 0; kq < 2; ++kq)                                    \
                A[t][kq] = *reinterpret_cast<const f16x8*>(                   \
                    pb + (t * 1024 + kq * 512 - 2048));                       \
    }

    ISSUE(0);
    for (int p = 0; p < NP; ++p) {
        const char* vb = smem + (p & 1) * 16384;
        char*       wb = smem + ((p + 1) & 1) * 16384;
        char*       ex = smem + 32768;

        f32x4 acc[4];
#pragma unroll
        for (int rg = 0; rg < 4; ++rg) acc[rg] = (f32x4){0.f, 0.f, 0.f, 0.f};

        u32 mq[4];
#pragma unroll
        for (int rg = 0; rg < 4; ++rg) mq[rg] = (u32)(bits[rg] >> (2 * p));

        __builtin_amdgcn_s_setprio(1);
#pragma unroll
        for (int kq = 0; kq < 2; ++kq) {
            f16x8 bfr[4];
#pragma unroll
            for (int rg = 0; rg < 4; ++rg)
                bfr[rg] = *reinterpret_cast<const f16x8*>(vb + rdoff[kq][rg]);
#pragma unroll
            for (int rg = 0; rg < 4; ++rg) {
                bool m0 = mq[rg] & 1;
                bool m1 = mq[rg] & 2;
                f16x8 vb0  = m0 ? bfr[rg] : zf;
                f16x8 vb1  = m1 ? bfr[rg] : zf;
                f16x8 vb01 = m1 ? vb0 : zf;
                acc[rg] = __builtin_amdgcn_mfma_f32_16x16x32_f16(
                    A[0][kq], bfr[rg], acc[rg], 0, 0, 0);
                acc[rg] = __builtin_amdgcn_mfma_f32_16x16x32_f16(
                    A[1][kq], vb0, acc[rg], 0, 0, 0);
                acc[rg] = __builtin_amdgcn_mfma_f32_16x16x32_f16(
                    A[2][kq], vb1, acc[rg], 0, 0, 0);
                acc[rg] = __builtin_amdgcn_mfma_f32_16x16x32_f16(
                    A[3][kq], vb01, acc[rg], 0, 0, 0);
            }
        }
        __builtin_amdgcn_s_setprio(0);

        if (p + 1 < NP) ISSUE(p + 1);   // in flight across the exchange phase

        // two-round cross-kh reduction + v_new write
#pragma unroll
        for (int R = 0; R < 2; ++R) {
            const int wr_rg = kh * 2 + R;          // partial I contribute
            const int kp_rg = (kh ^ 1) * 2 + R;    // row-group I complete
            *reinterpret_cast<f32x4*>(ex + exoff_w) = acc[wr_rg];
            __syncthreads();
            f32x4 part = *reinterpret_cast<const f32x4*>(ex + exoff_r);
            acc[kp_rg] += part;
            if (p < NP - 1) {
                u32 lo = ((u32)f2h(acc[kp_rg][1]) << 16) | f2h(acc[kp_rg][0]);
                u32 hi = ((u32)f2h(acc[kp_rg][3]) << 16) | f2h(acc[kp_rg][2]);
                uint2 w = {lo, hi};
                *reinterpret_cast<uint2*>(wb + wroff[R]) = w;
            } else {
                int mcol = mt * 16 + g * 4;
                const float4 rv = *reinterpret_cast<const float4*>(right + mcol);
                pvs[R] = acc[kp_rg][0] * rv.x + acc[kp_rg][1] * rv.y +
                         acc[kp_rg][2] * rv.z + acc[kp_rg][3] * rv.w;
            }
            __syncthreads();
        }
    }
#undef ISSUE

    // epilogue: reduce pvs over the 4 g-lanes, then across mt via LDS
    char* red = smem + 32768;   // overlays exchange buffer (dead now)
#pragma unroll
    for (int R = 0; R < 2; ++R) {
        float pv = pvs[R];
        pv += __shfl_xor(pv, 16, 64);
        pv += __shfl_xor(pv, 32, 64);
        int rgk = (kh ? 0 : 2) + R;
        int r = rgk * 16 + li;
        if (g == 0)
            *reinterpret_cast<float*>(red + (r * 8 + mt) * 4) = pv;
    }
    __syncthreads();
    if (tid < 64) {
        float s = 0.f;
#pragma unroll
        for (int i = 0; i < 8; ++i)
            s += *reinterpret_cast<float*>(red + (tid * 8 + i) * 4);
        out[rbase + tid] = s;
    }
}

// ---------------------------------------------------------------------------
extern "C" void kernel_launch(void* const* d_in, const int* in_sizes, int n_in,
                              void* d_out, int out_size, void* d_ws, size_t ws_size,
                              hipStream_t stream) {
    const int*   onstate = (const int*)d_in[0];
    const float* data    = (const float*)d_in[1];
    const float* left    = (const float*)d_in[2];
    const float* right   = (const float*)d_in[3];
    const int*   image2  = (const int*)d_in[4];
    float* out = (float*)d_out;

    unsigned short* afrag = (unsigned short*)d_ws;                       // 4 MB
    u64* bits = (u64*)((char*)d_ws + (size_t)2097152 * sizeof(unsigned short));

    prep_pair_frags<<<256, 256, 0, stream>>>(data, afrag);
    prep_bits<<<64, 256, 0, stream>>>(onstate, image2, bits);
    mps_pair<<<256, 1024, 0, stream>>>(afrag, bits, left, right, out);
}

// Round 10
// 167.861 us; speedup vs baseline: 1.4641x; 1.4641x over previous
//
#include <hip/hip_runtime.h>
#include <hip/hip_bf16.h>

#define NS 64
#define NP 32
#define DIM 128
#define BATCH_N 16384

typedef float f32x4 __attribute__((ext_vector_type(4)));
typedef _Float16 f16x8 __attribute__((ext_vector_type(8)));
typedef unsigned int u32;
typedef unsigned long long u64;

// fp32 -> fp16 (RNE via hardware cvt)
__device__ __forceinline__ unsigned short f2h(float f) {
    _Float16 h = (_Float16)f;
    return __builtin_bit_cast(unsigned short, h);
}

// ---------------------------------------------------------------------------
// prep 1: pair-compressed fp16 MFMA A-operand fragments (unchanged, verified).
//   t0 = A0@B0            t1 = (A1-A0)@B0      (factor b0)
//   t2 = A0@(B1-B0)       t3 = (A1-A0)@(B1-B0) (factor b0*b1)
// element idx = ((((p*8 + mm)*2 + H)*4 + t)*2 + kq)*512 + lane*8 + j
// kk = 2H+kq, k = kk*32 + (lane>>4)*8 + j, m = mm*16 + (lane&15).
// ---------------------------------------------------------------------------
__global__ __launch_bounds__(256)
void prep_pair_frags(const float* __restrict__ data,
                     unsigned short* __restrict__ afrag) {
    __shared__ float LA[2 * 32 * 129];
    __shared__ float LB[2 * 32 * 68];

    const int p   = blockIdx.x >> 3;
    const int kk  = (blockIdx.x >> 1) & 3;
    const int mh  = blockIdx.x & 1;
    const int tid = threadIdx.x;
    const int kgrp = tid >> 4;
    const int mgrp = tid & 15;

    const float* A0 = data + ((size_t)(2 * p) * 2 + 0) * DIM * DIM;
    const float* A1 = A0 + DIM * DIM;
    const float* B0 = data + ((size_t)(2 * p + 1) * 2 + 0) * DIM * DIM;
    const float* B1 = B0 + DIM * DIM;

    for (int c = tid; c < 32 * DIM; c += 256) {
        int kl = c >> 7, j = c & 127;
        float a0 = A0[(kk * 32 + kl) * DIM + j];
        float a1 = A1[(kk * 32 + kl) * DIM + j];
        LA[kl * 129 + j] = a0;
        LA[32 * 129 + kl * 129 + j] = a1 - a0;
    }

    float acc[2][2][2][4];
#pragma unroll
    for (int L = 0; L < 2; ++L)
#pragma unroll
        for (int R = 0; R < 2; ++R)
#pragma unroll
            for (int i = 0; i < 2; ++i)
#pragma unroll
                for (int mi = 0; mi < 4; ++mi) acc[L][R][i][mi] = 0.f;

    for (int ch = 0; ch < 4; ++ch) {
        __syncthreads();
        for (int c = tid; c < 32 * 64; c += 256) {
            int jl = c >> 6, ml = c & 63;
            float b0 = B0[(ch * 32 + jl) * DIM + mh * 64 + ml];
            float b1 = B1[(ch * 32 + jl) * DIM + mh * 64 + ml];
            LB[jl * 68 + ml] = b0;
            LB[32 * 68 + jl * 68 + ml] = b1 - b0;
        }
        __syncthreads();
#pragma unroll 2
        for (int jl = 0; jl < 32; ++jl) {
            int j = ch * 32 + jl;
            float la0[2], la1[2];
#pragma unroll
            for (int i = 0; i < 2; ++i) {
                la0[i] = LA[(kgrp * 2 + i) * 129 + j];
                la1[i] = LA[32 * 129 + (kgrp * 2 + i) * 129 + j];
            }
            f32x4 lb0 = *reinterpret_cast<const f32x4*>(&LB[jl * 68 + mgrp * 4]);
            f32x4 lb1 = *reinterpret_cast<const f32x4*>(&LB[32 * 68 + jl * 68 + mgrp * 4]);
#pragma unroll
            for (int i = 0; i < 2; ++i)
#pragma unroll
                for (int mi = 0; mi < 4; ++mi) {
                    acc[0][0][i][mi] += la0[i] * lb0[mi];
                    acc[1][0][i][mi] += la1[i] * lb0[mi];
                    acc[0][1][i][mi] += la0[i] * lb1[mi];
                    acc[1][1][i][mi] += la1[i] * lb1[mi];
                }
        }
    }

    const int H  = kk >> 1;
    const int kq = kk & 1;
#pragma unroll
    for (int t = 0; t < 4; ++t) {
        int L = t & 1, R = t >> 1;
#pragma unroll
        for (int i = 0; i < 2; ++i)
#pragma unroll
            for (int mi = 0; mi < 4; ++mi) {
                int k = kk * 32 + kgrp * 2 + i;
                int m = mh * 64 + mgrp * 4 + mi;
                int mm = m >> 4;
                int lane = ((k & 31) >> 3) * 16 + (m & 15);
                int jj = k & 7;
                size_t idx =
                    ((size_t)((((p * 8 + mm) * 2 + H) * 4 + t) * 2 + kq)) * 512 +
                    lane * 8 + jj;
                afrag[idx] = f2h(acc[L][R][i][mi]);
            }
    }
}

// ---------------------------------------------------------------------------
// prep 2: pack occupation bits, one u64 per batch row
// ---------------------------------------------------------------------------
__global__ void prep_bits(const int* __restrict__ onstate,
                          const int* __restrict__ image2,
                          u64* __restrict__ bits) {
    int r = blockIdx.x * blockDim.x + threadIdx.x;
    if (r >= BATCH_N) return;
    const int* row = onstate + (size_t)r * NS;
    u64 b = 0;
#pragma unroll 8
    for (int t = 0; t < NS; ++t) {
        b |= ((u64)(row[image2[t]] & 1)) << t;
    }
    bits[r] = b;
}

// ---------------------------------------------------------------------------
// main: 256 blocks x 1024 threads (16 waves, 4/SIMD), 64 rows, 1 block/CU.
// Wave (mt = wid>>1, kh = wid&1): m-tile 16 x K-half 64. Zero A-duplication.
// Single-round cross-kh exchange (32 KB buffer), 2 barriers/pair. All
// register-array indices are compile-time constants (rule #20: R8's runtime
// kh-indexing of acc[] demoted registers -> 6x VALU explosion).
// ---------------------------------------------------------------------------
__global__ __launch_bounds__(1024, 4)
void mps_pair(const unsigned short* __restrict__ afrag,
              const u64* __restrict__ occbits,
              const float* __restrict__ left,
              const float* __restrict__ right,
              float* __restrict__ out) {
    __shared__ char smem[65536];   // [0,32K): v dbuf fp16 swizzled; [32K,64K): exchange

    const int tid  = threadIdx.x;
    const int wid  = tid >> 6;          // 0..15
    const int mt   = wid >> 1;          // 0..7: m-tile
    const int kh   = wid & 1;           // 0..1: K-half
    const int lane = tid & 63;
    const int li   = lane & 15;
    const int g    = lane >> 4;
    const int rbase = blockIdx.x * 64;

    u64 bits[4];
#pragma unroll
    for (int rg = 0; rg < 4; ++rg)
        bits[rg] = occbits[rbase + rg * 16 + li];

    // A-frag element voffset (saddr layout), +2048 centers imm range
    const int voff = (mt * 2 + kh) * 4096 + 2048 + lane * 8;

    // v-read byte offsets [kq][rg] (kk = kh*2+kq)
    u32 rdoff[2][4];
#pragma unroll
    for (int kq = 0; kq < 2; ++kq)
#pragma unroll
        for (int rg = 0; rg < 4; ++rg) {
            int r = rg * 16 + li;
            int kk = kh * 2 + kq;
            rdoff[kq][rg] =
                (u32)(r * 256 + kk * 64 + g * 16) ^ ((u32)(r & 7) << 4);
        }

    // exchange slots: [mt][rg][lane] f32x4. I write the rg's I do NOT keep,
    // read the rg's I keep. kh=0 keeps rg{0,1}, kh=1 keeps rg{2,3}.
    const u32 exw0 = (u32)(((mt * 4 + (kh ? 0 : 2)) * 64 + lane) * 16);
    const u32 exw1 = exw0 + 1024;
    const u32 exr0 = (u32)(((mt * 4 + (kh ? 2 : 0)) * 64 + lane) * 16);
    const u32 exr1 = exr0 + 1024;

    // v-write byte offsets for kept rows (R = 0,1)
    u32 wroff[2];
#pragma unroll
    for (int R = 0; R < 2; ++R) {
        int r = ((kh ? 2 : 0) + R) * 16 + li;
        wroff[R] = (u32)(r * 256 + (mt * 16 + g * 4) * 2) ^ ((u32)(r & 7) << 4);
    }

    // init v buffer 0 with fp16(left), swizzled (1024 thr = 64 rows x 16 chunks)
    {
        int r  = tid >> 4;
        int kc = tid & 15;
        unsigned short tmp[8];
#pragma unroll
        for (int j = 0; j < 8; ++j) tmp[j] = f2h(left[kc * 8 + j]);
        u32 byte = (u32)(r * 256 + kc * 16) ^ ((u32)(r & 7) << 4);
        *reinterpret_cast<uint4*>(smem + byte) = *reinterpret_cast<uint4*>(tmp);
    }
    __syncthreads();

    const f16x8 zf = {0, 0, 0, 0, 0, 0, 0, 0};
    f16x8 A[4][2];     // [t][kq]; reloaded during exchange phase (single buffer)
    float pvs0 = 0.f, pvs1 = 0.f;

#define ISSUE(P_)                                                             \
    {                                                                         \
        const unsigned short* pb = afrag + (size_t)(P_)*65536 + voff;         \
        _Pragma("unroll")                                                     \
        for (int t = 0; t < 4; ++t)                                           \
            _Pragma("unroll")                                                 \
            for (int kq = 0; kq < 2; ++kq)                                    \
                A[t][kq] = *reinterpret_cast<const f16x8*>(                   \
                    pb + (t * 1024 + kq * 512 - 2048));                       \
    }

    ISSUE(0);
    for (int p = 0; p < NP; ++p) {
        const char* vb = smem + (p & 1) * 16384;
        char*       wb = smem + ((p + 1) & 1) * 16384;
        char*       ex = smem + 32768;

        f32x4 acc[4];
#pragma unroll
        for (int rg = 0; rg < 4; ++rg) acc[rg] = (f32x4){0.f, 0.f, 0.f, 0.f};

        u32 mq[4];
#pragma unroll
        for (int rg = 0; rg < 4; ++rg) mq[rg] = (u32)(bits[rg] >> (2 * p));

        __builtin_amdgcn_s_setprio(1);
#pragma unroll
        for (int kq = 0; kq < 2; ++kq) {
            f16x8 bfr[4];
#pragma unroll
            for (int rg = 0; rg < 4; ++rg)
                bfr[rg] = *reinterpret_cast<const f16x8*>(vb + rdoff[kq][rg]);
#pragma unroll
            for (int rg = 0; rg < 4; ++rg) {
                bool m0 = mq[rg] & 1;
                bool m1 = mq[rg] & 2;
                f16x8 vb0  = m0 ? bfr[rg] : zf;
                f16x8 vb1  = m1 ? bfr[rg] : zf;
                f16x8 vb01 = m1 ? vb0 : zf;
                acc[rg] = __builtin_amdgcn_mfma_f32_16x16x32_f16(
                    A[0][kq], bfr[rg], acc[rg], 0, 0, 0);
                acc[rg] = __builtin_amdgcn_mfma_f32_16x16x32_f16(
                    A[1][kq], vb0, acc[rg], 0, 0, 0);
                acc[rg] = __builtin_amdgcn_mfma_f32_16x16x32_f16(
                    A[2][kq], vb1, acc[rg], 0, 0, 0);
                acc[rg] = __builtin_amdgcn_mfma_f32_16x16x32_f16(
                    A[3][kq], vb01, acc[rg], 0, 0, 0);
            }
        }
        __builtin_amdgcn_s_setprio(0);

        if (p + 1 < NP) ISSUE(p + 1);   // in flight across the exchange phase

        // single-round exchange; STATIC acc indices in each wave-uniform branch
        if (kh == 0) {
            *reinterpret_cast<f32x4*>(ex + exw0) = acc[2];
            *reinterpret_cast<f32x4*>(ex + exw1) = acc[3];
        } else {
            *reinterpret_cast<f32x4*>(ex + exw0) = acc[0];
            *reinterpret_cast<f32x4*>(ex + exw1) = acc[1];
        }
        __syncthreads();
        f32x4 p0 = *reinterpret_cast<const f32x4*>(ex + exr0);
        f32x4 p1 = *reinterpret_cast<const f32x4*>(ex + exr1);
        f32x4 keep0, keep1;
        if (kh == 0) {
            keep0 = acc[0] + p0;
            keep1 = acc[1] + p1;
        } else {
            keep0 = acc[2] + p0;
            keep1 = acc[3] + p1;
        }

        if (p < NP - 1) {
            u32 lo0 = ((u32)f2h(keep0[1]) << 16) | f2h(keep0[0]);
            u32 hi0 = ((u32)f2h(keep0[3]) << 16) | f2h(keep0[2]);
            uint2 w0 = {lo0, hi0};
            *reinterpret_cast<uint2*>(wb + wroff[0]) = w0;
            u32 lo1 = ((u32)f2h(keep1[1]) << 16) | f2h(keep1[0]);
            u32 hi1 = ((u32)f2h(keep1[3]) << 16) | f2h(keep1[2]);
            uint2 w1 = {lo1, hi1};
            *reinterpret_cast<uint2*>(wb + wroff[1]) = w1;
        } else {
            int mcol = mt * 16 + g * 4;
            const float4 rv = *reinterpret_cast<const float4*>(right + mcol);
            pvs0 = keep0[0] * rv.x + keep0[1] * rv.y +
                   keep0[2] * rv.z + keep0[3] * rv.w;
            pvs1 = keep1[0] * rv.x + keep1[1] * rv.y +
                   keep1[2] * rv.z + keep1[3] * rv.w;
        }
        __syncthreads();
    }
#undef ISSUE

    // epilogue: reduce over g-lanes (shfl), then across mt via LDS
    char* red = smem + 32768;   // overlays exchange buffer (dead)
    {
        float pv = pvs0;
        pv += __shfl_xor(pv, 16, 64);
        pv += __shfl_xor(pv, 32, 64);
        int r = ((kh ? 2 : 0) + 0) * 16 + li;
        if (g == 0)
            *reinterpret_cast<float*>(red + (r * 8 + mt) * 4) = pv;
    }
    {
        float pv = pvs1;
        pv += __shfl_xor(pv, 16, 64);
        pv += __shfl_xor(pv, 32, 64);
        int r = ((kh ? 2 : 0) + 1) * 16 + li;
        if (g == 0)
            *reinterpret_cast<float*>(red + (r * 8 + mt) * 4) = pv;
    }
    __syncthreads();
    if (tid < 64) {
        float s = 0.f;
#pragma unroll
        for (int i = 0; i < 8; ++i)
            s += *reinterpret_cast<float*>(red + (tid * 8 + i) * 4);
        out[rbase + tid] = s;
    }
}

// ---------------------------------------------------------------------------
extern "C" void kernel_launch(void* const* d_in, const int* in_sizes, int n_in,
                              void* d_out, int out_size, void* d_ws, size_t ws_size,
                              hipStream_t stream) {
    const int*   onstate = (const int*)d_in[0];
    const float* data    = (const float*)d_in[1];
    const float* left    = (const float*)d_in[2];
    const float* right   = (const float*)d_in[3];
    const int*   image2  = (const int*)d_in[4];
    float* out = (float*)d_out;

    unsigned short* afrag = (unsigned short*)d_ws;                       // 4 MB
    u64* bits = (u64*)((char*)d_ws + (size_t)2097152 * sizeof(unsigned short));

    prep_pair_frags<<<256, 256, 0, stream>>>(data, afrag);
    prep_bits<<<64, 256, 0, stream>>>(onstate, image2, bits);
    mps_pair<<<256, 1024, 0, stream>>>(afrag, bits, left, right, out);
}